// Round 4
// baseline (2198.105 us; speedup 1.0000x reference)
//
#include <hip/hip_runtime.h>
#include <hip/hip_bf16.h>

// ---------------------------------------------------------------------------
// KAN net. Rows b = w*2048 + n; xa[b,i] = x[n*8464 + i*16 + w].
// k_l12:      layer1(529->40) + layer2(40->60) fused -> h2d[n][o*16+w] (2048x960)
// k_lin1head: lin1(960->512) + l2norm + spline-act + lin2(512->16) + l2norm
//             -> OUTPUT IS FLOAT32 (reference returns jnp.float32).
// Workspace: 10.25 MB. Closed-form B-spline validated bit-identical (at the
// output) to the literal Cox-de Boor transcription in the r2 bisection build.
// ---------------------------------------------------------------------------

__device__ __forceinline__ float siluf(float x) { return x / (1.f + __expf(-x)); }

// Dense 8-wide cubic B-spline basis, uniform grid t_j = (j-3)*0.4 - 1 (j=0..11).
// Valid cells c = floor((x+2.2)*2.5) in [0,10]; outside support -> all zeros.
__device__ __forceinline__ void bspline8(float x, float fm[8]) {
    float tpos = (x + 2.2f) * 2.5f;
    float fc = floorf(tpos);
    int c = (int)fc;
    float u = tpos - fc;
    bool valid = (c >= 0) && (c <= 10);
    float om = 1.f - u;
    float u2 = u * u, u3 = u2 * u;
    float W0 = om * om * om * (1.f / 6.f);                   // m = c-3
    float W1 = (3.f * u3 - 6.f * u2 + 4.f) * (1.f / 6.f);    // m = c-2
    float W2 = (-3.f * u3 + 3.f * u2 + 3.f * u + 1.f) * (1.f / 6.f); // m = c-1
    float W3 = u3 * (1.f / 6.f);                             // m = c
#pragma unroll
    for (int m = 0; m < 8; ++m) {
        int d = c - m;
        float v = (d == 3) ? W0 : 0.f;
        v = (d == 2) ? W1 : v;
        v = (d == 1) ? W2 : v;
        v = (d == 0) ? W3 : v;
        fm[m] = valid ? v : 0.f;
    }
}

#define FMA9(a, w9)                                   \
    do {                                              \
        a = fmaf(s,     (w9)[0], a);                  \
        a = fmaf(fm[0], (w9)[1], a);                  \
        a = fmaf(fm[1], (w9)[2], a);                  \
        a = fmaf(fm[2], (w9)[3], a);                  \
        a = fmaf(fm[3], (w9)[4], a);                  \
        a = fmaf(fm[4], (w9)[5], a);                  \
        a = fmaf(fm[5], (w9)[6], a);                  \
        a = fmaf(fm[6], (w9)[7], a);                  \
        a = fmaf(fm[7], (w9)[8], a);                  \
    } while (0)

// ---------------------------------------------------------------------------
// prep: weight re-layouts (zero-padded where noted)
//   w1t[i][o][9]  i<576 (i>=529 zero), o<40 : slot0=base_w, slot1..8=spline_w
//   w2t[i][o][9]  i<40, o<60
//   wq [dq][u][4] = lin1_w[u][dq*4+r], dq<240, u<512
// ---------------------------------------------------------------------------
__global__ __launch_bounds__(256) void k_prep(
    const float* __restrict__ base_w1, const float* __restrict__ spline_w1,
    const float* __restrict__ base_w2, const float* __restrict__ spline_w2,
    const float* __restrict__ lin1_w,
    float* __restrict__ w1t, float* __restrict__ w2t, float* __restrict__ wq) {
    int gid = blockIdx.x * 256 + threadIdx.x;
    int stride = gridDim.x * 256;
    for (int idx = gid; idx < 576 * 360; idx += stride) {
        int i = idx / 360;
        int rem = idx - i * 360;
        int o = rem / 9;
        int g = rem - o * 9;
        float v = 0.f;
        if (i < 529)
            v = (g == 0) ? base_w1[o * 529 + i]
                         : spline_w1[(o * 529 + i) * 8 + (g - 1)];
        w1t[idx] = v;
    }
    for (int idx = gid; idx < 40 * 540; idx += stride) {
        int i = idx / 540;
        int rem = idx - i * 540;
        int o = rem / 9;
        int g = rem - o * 9;
        w2t[idx] = (g == 0) ? base_w2[o * 40 + i]
                            : spline_w2[(o * 40 + i) * 8 + (g - 1)];
    }
    for (int idx = gid; idx < 240 * 512 * 4; idx += stride) {
        int dq = idx >> 11;
        int rem = idx & 2047;
        int u = rem >> 2;
        int r = rem & 3;
        wq[idx] = lin1_w[u * 960 + dq * 4 + r];
    }
}

// ---------------------------------------------------------------------------
// k_l12: 256 blocks x 256 threads. Block = 128 rows (nn=0..7, w=0..15),
// n0 = blockIdx*8. 2-way i-split (g = t>>7), row r = t&127. Layer1 partials
// reduced through LDS, layer2 in-block, store h2d[n][o*16+w].
// ---------------------------------------------------------------------------
__global__ __launch_bounds__(256) void k_l12(
    const float* __restrict__ x, const float* __restrict__ w1t,
    const float* __restrict__ w2t, float* __restrict__ h2d) {
    __shared__ float xs[32][128];         // 16 KB
    __shared__ float part[2][128][40];    // 40 KB
    int t = threadIdx.x;
    int g = t >> 7;
    int r = t & 127;
    int n0 = blockIdx.x * 8;

    float acc[40];
#pragma unroll
    for (int o = 0; o < 40; ++o) acc[o] = 0.f;

#pragma unroll 1
    for (int sc = 0; sc < 18; ++sc) {     // 18 * 32 = 576 >= 529
        int i0 = sc * 32;
        __syncthreads();
#pragma unroll
        for (int j = 0; j < 16; ++j) {    // stage 32i x 128r
            int e = j * 256 + t;
            int il = e >> 7;
            int rr = e & 127;
            int i = i0 + il;
            float v = 0.f;
            if (i < 529)
                v = x[(size_t)(n0 + (rr >> 4)) * 8464 + (size_t)i * 16 + (rr & 15)];
            xs[il][rr] = v;
        }
        __syncthreads();
#pragma unroll 1
        for (int ii = 0; ii < 16; ++ii) {
            int i = i0 + g * 16 + ii;
            float xv = xs[g * 16 + ii][r];
            float s = siluf(xv);
            float fm[8];
            bspline8(xv, fm);
            const float* wp = w1t + (size_t)i * 360;   // wave-uniform -> s_load
#pragma unroll
            for (int o = 0; o < 40; ++o) {
                const float* w9 = wp + o * 9;
                float a = acc[o];
                FMA9(a, w9);
                acc[o] = a;
            }
        }
    }
#pragma unroll
    for (int o = 0; o < 40; ++o) part[g][r][o] = acc[o];
    __syncthreads();

    // layer2: thread = (row r2, output-half oh), 30 outputs
    int r2 = t & 127;
    int oh = t >> 7;
    float acc2[30];
#pragma unroll
    for (int oo = 0; oo < 30; ++oo) acc2[oo] = 0.f;

#pragma unroll 1
    for (int i = 0; i < 40; ++i) {
        float hv = part[0][r2][i] + part[1][r2][i];
        float s = siluf(hv);
        float fm[8];
        bspline8(hv, fm);
        const float* wp = w2t + i * 540 + oh * 270;    // wave-uniform -> s_load
#pragma unroll
        for (int oo = 0; oo < 30; ++oo) {
            const float* w9 = wp + oo * 9;
            float a = acc2[oo];
            FMA9(a, w9);
            acc2[oo] = a;
        }
    }
    float* op = h2d + (size_t)(n0 + (r2 >> 4)) * 960 + (r2 & 15);
#pragma unroll
    for (int oo = 0; oo < 30; ++oo) op[(size_t)(oh * 30 + oo) * 16] = acc2[oo];
}

// ---------------------------------------------------------------------------
// k_lin1head: 256 blocks x 256 threads, block = 8 rows (n0 = blockIdx*8).
// Stage H rows in LDS -> lin1 (thread owns u=t and u=t+256) -> h3 back into
// the same LDS buffer -> per-wave head (2 rows/wave). FLOAT32 output.
// ---------------------------------------------------------------------------
__global__ __launch_bounds__(256) void k_lin1head(
    const float* __restrict__ h2d, const float* __restrict__ wq,
    const float* __restrict__ lin1_b, const float* __restrict__ act_base,
    const float* __restrict__ act_coeff, const float* __restrict__ lin2_w,
    const float* __restrict__ lin2_b, float* __restrict__ out) {
    __shared__ float smem[8 * 960];   // 30.7 KB; reused as h3[8][512]
    int t = threadIdx.x;
    int n0 = blockIdx.x * 8;

#pragma unroll 1
    for (int e = t; e < 7680; e += 256)
        smem[e] = h2d[(size_t)n0 * 960 + e];
    __syncthreads();

    float acc0[8], acc1[8];
#pragma unroll
    for (int nn = 0; nn < 8; ++nn) { acc0[nn] = 0.f; acc1[nn] = 0.f; }

    const float4* wq4 = (const float4*)wq;
#pragma unroll 1
    for (int dq = 0; dq < 240; ++dq) {
        float4 w0 = wq4[(size_t)dq * 512 + t];
        float4 w1 = wq4[(size_t)dq * 512 + t + 256];
#pragma unroll
        for (int nn = 0; nn < 8; ++nn) {
            float4 rv = *(const float4*)&smem[nn * 960 + dq * 4];  // broadcast
            float a0 = acc0[nn], a1 = acc1[nn];
            a0 = fmaf(rv.x, w0.x, a0); a1 = fmaf(rv.x, w1.x, a1);
            a0 = fmaf(rv.y, w0.y, a0); a1 = fmaf(rv.y, w1.y, a1);
            a0 = fmaf(rv.z, w0.z, a0); a1 = fmaf(rv.z, w1.z, a1);
            a0 = fmaf(rv.w, w0.w, a0); a1 = fmaf(rv.w, w1.w, a1);
            acc0[nn] = a0; acc1[nn] = a1;
        }
    }
    float b0 = lin1_b[t];
    float b1 = lin1_b[t + 256];
    __syncthreads();                       // done reading H from smem
#pragma unroll
    for (int nn = 0; nn < 8; ++nn) {
        smem[nn * 512 + t] = acc0[nn] + b0;
        smem[nn * 512 + t + 256] = acc1[nn] + b1;
    }
    __syncthreads();

    int wvv = t >> 6, lane = t & 63;
#pragma unroll 1
    for (int rr = 0; rr < 2; ++rr) {
        int row = wvv * 2 + rr;
        int n = n0 + row;
        const float* hr = smem + row * 512;

        float xv[8];
#pragma unroll
        for (int k = 0; k < 8; ++k) xv[k] = hr[lane + 64 * k];
        float ss = 0.f;
#pragma unroll
        for (int k = 0; k < 8; ++k) ss = fmaf(xv[k], xv[k], ss);
#pragma unroll
        for (int d = 1; d < 64; d <<= 1) ss += __shfl_xor(ss, d, 64);
        float scale = 1.f / fmaxf(sqrtf(ss), 1e-12f);

        float act[8];
#pragma unroll
        for (int k = 0; k < 8; ++k) {
            int u = lane + 64 * k;
            float hn = xv[k] * scale;
            float s = siluf(hn);
            float fm[8];
            bspline8(hn, fm);
            float4 c0 = *(const float4*)(act_coeff + (size_t)u * 8);
            float4 c1 = *(const float4*)(act_coeff + (size_t)u * 8 + 4);
            float a = act_base[u] * s;
            a = fmaf(fm[0], c0.x, a);
            a = fmaf(fm[1], c0.y, a);
            a = fmaf(fm[2], c0.z, a);
            a = fmaf(fm[3], c0.w, a);
            a = fmaf(fm[4], c1.x, a);
            a = fmaf(fm[5], c1.y, a);
            a = fmaf(fm[6], c1.z, a);
            a = fmaf(fm[7], c1.w, a);
            act[k] = a;
        }

        float y = 0.f;
#pragma unroll
        for (int v = 0; v < 16; ++v) {
            float pv = 0.f;
#pragma unroll
            for (int k = 0; k < 8; ++k)
                pv = fmaf(act[k], lin2_w[v * 512 + lane + 64 * k], pv);
#pragma unroll
            for (int d = 1; d < 64; d <<= 1) pv += __shfl_xor(pv, d, 64);
            if (lane == v) y = pv + lin2_b[v];
        }
        float q = y * y;                   // lanes >= 16 hold y = 0
#pragma unroll
        for (int d = 1; d < 16; d <<= 1) q += __shfl_xor(q, d, 64);
        float sc2 = 1.f / fmaxf(sqrtf(q), 1e-12f);
        if (lane < 16)
            out[(size_t)n * 16 + lane] = y * sc2;      // FLOAT32 store
    }
}

// ---------------------------------------------------------------------------
extern "C" void kernel_launch(void* const* d_in, const int* in_sizes, int n_in,
                              void* d_out, int out_size, void* d_ws,
                              size_t ws_size, hipStream_t stream) {
    auto find = [&](int sz, int occur) -> const float* {
        int seen = 0;
        for (int i = 0; i < n_in; ++i) {
            if (in_sizes[i] == sz) {
                if (seen == occur) return (const float*)d_in[i];
                ++seen;
            }
        }
        return nullptr;
    };
    const float* x         = find(17334272, 0);
    const float* base_w1   = find(21160, 0);
    const float* spline_w1 = find(169280, 0);
    const float* base_w2   = find(2400, 0);
    const float* spline_w2 = find(19200, 0);
    const float* lin1_w    = find(491520, 0);
    const float* lin1_b    = find(512, 0);   // first 512-vec in dict order
    const float* act_base  = find(512, 1);   // second
    const float* act_coeff = find(4096, 0);
    const float* lin2_w    = find(8192, 0);
    const float* lin2_b    = find(16, 0);
    if (!x || !base_w1 || !spline_w1 || !base_w2 || !spline_w2 || !lin1_w ||
        !lin1_b || !act_base || !act_coeff || !lin2_w || !lin2_b) {
        x         = (const float*)d_in[0];
        base_w1   = (const float*)d_in[3];
        spline_w1 = (const float*)d_in[4];
        base_w2   = (const float*)d_in[6];
        spline_w2 = (const float*)d_in[7];
        lin1_w    = (const float*)d_in[8];
        lin1_b    = (const float*)d_in[9];
        act_base  = (const float*)d_in[11];
        act_coeff = (const float*)d_in[12];
        lin2_w    = (const float*)d_in[13];
        lin2_b    = (const float*)d_in[14];
    }

    float* ws  = (float*)d_ws;
    float* w1t = ws;                 // 576*360    = 207360 floats
    float* w2t = w1t + 207360;       // 40*540     = 21600
    float* wq  = w2t + 21600;        // 240*512*4  = 491520
    float* h2d = wq + 491520;        // 2048*960   = 1966080
    // total 2,686,560 floats = 10.25 MB

    k_prep<<<1024, 256, 0, stream>>>(base_w1, spline_w1, base_w2, spline_w2,
                                     lin1_w, w1t, w2t, wq);
    k_l12<<<256, 256, 0, stream>>>(x, w1t, w2t, h2d);
    k_lin1head<<<256, 256, 0, stream>>>(h2d, wq, lin1_b, act_base, act_coeff,
                                        lin2_w, lin2_b, (float*)d_out);
}

// Round 5
// 514.197 us; speedup vs baseline: 4.2748x; 4.2748x over previous
//
#include <hip/hip_runtime.h>

// ---------------------------------------------------------------------------
// KAN net. Rows b = w*2048 + n; xa[b,i] = x[n*8464 + i*16 + w].
// k_l12:      layer1(529->40) + layer2(40->60) fused -> h2d[n][o*16+w]
//             512 blocks x 512 thr; wave = 64 rows x 1 i-split (8 splits).
//             Weights via readfirstlane-uniform s_load (SGPR FMA operands).
// k_lin1head: lin1(960->512) + l2norm + spline-act + lin2 + l2norm -> f32 out
// Workspace 10.2 MB.
// ---------------------------------------------------------------------------

__device__ __forceinline__ float siluf(float x) { return x / (1.f + __expf(-x)); }

// Dense 8-wide cubic B-spline on uniform grid t_j = (j-3)*0.4 - 1 (validated
// bit-identical to literal Cox-de Boor in the r2 bisection build).
__device__ __forceinline__ void bspline8(float x, float fm[8]) {
    float tpos = (x + 2.2f) * 2.5f;
    float fc = floorf(tpos);
    int c = (int)fc;
    float u = tpos - fc;
    bool valid = (c >= 0) && (c <= 10);
    float om = 1.f - u;
    float u2 = u * u, u3 = u2 * u;
    float W0 = om * om * om * (1.f / 6.f);
    float W1 = (3.f * u3 - 6.f * u2 + 4.f) * (1.f / 6.f);
    float W2 = (-3.f * u3 + 3.f * u2 + 3.f * u + 1.f) * (1.f / 6.f);
    float W3 = u3 * (1.f / 6.f);
#pragma unroll
    for (int m = 0; m < 8; ++m) {
        int d = c - m;
        float v = (d == 3) ? W0 : 0.f;
        v = (d == 2) ? W1 : v;
        v = (d == 1) ? W2 : v;
        v = (d == 0) ? W3 : v;
        fm[m] = valid ? v : 0.f;
    }
}

// ---------------------------------------------------------------------------
// prep: weight re-layouts
//   w1t[i][q][40]  i<529, q<9 : q0 = base_w1, q1..8 = spline_w1 (16B-aligned)
//   w2t[i][q][60]  i<40
//   wq [dq][u][4]  = lin1_w[u][dq*4+r]
// ---------------------------------------------------------------------------
__global__ __launch_bounds__(256) void k_prep(
    const float* __restrict__ base_w1, const float* __restrict__ spline_w1,
    const float* __restrict__ base_w2, const float* __restrict__ spline_w2,
    const float* __restrict__ lin1_w,
    float* __restrict__ w1t, float* __restrict__ w2t, float* __restrict__ wq) {
    int gid = blockIdx.x * 256 + threadIdx.x;
    int stride = gridDim.x * 256;
    for (int idx = gid; idx < 529 * 360; idx += stride) {
        int i = idx / 360;
        int rem = idx - i * 360;
        int q = rem / 40;
        int o = rem - q * 40;
        w1t[idx] = (q == 0) ? base_w1[o * 529 + i]
                            : spline_w1[(o * 529 + i) * 8 + (q - 1)];
    }
    for (int idx = gid; idx < 40 * 540; idx += stride) {
        int i = idx / 540;
        int rem = idx - i * 540;
        int q = rem / 60;
        int o = rem - q * 60;
        w2t[idx] = (q == 0) ? base_w2[o * 40 + i]
                            : spline_w2[(o * 40 + i) * 8 + (q - 1)];
    }
    for (int idx = gid; idx < 240 * 512 * 4; idx += stride) {
        int dq = idx >> 11;
        int rem = idx & 2047;
        int u = rem >> 2;
        int r = rem & 3;
        wq[idx] = lin1_w[u * 960 + dq * 4 + r];
    }
}

// ---------------------------------------------------------------------------
// k_l12: 512 blocks x 512 threads. Block = 64 rows (4 n x 16 w), n0 = blk*4.
// Wave g = t>>6 owns i in [g*67, min(g*67+67,529)); lane r = row.
// x read direct from global (no reuse). Weights: uniform s_load.
// Partials part[8][40][64] (80 KB, conflict-free), layer2 in-block.
// ---------------------------------------------------------------------------
__global__ __launch_bounds__(512) void k_l12(
    const float* __restrict__ x, const float* __restrict__ w1t,
    const float* __restrict__ w2t, float* __restrict__ h2d) {
    __shared__ float part[8][40][64];   // 80 KB
    int t = threadIdx.x;
    int g = t >> 6;
    int r = t & 63;
    int n0 = blockIdx.x * 4;
    const float* xp = x + (size_t)(n0 + (r >> 4)) * 8464 + (r & 15);

    float acc[40];
#pragma unroll
    for (int o = 0; o < 40; ++o) acc[o] = 0.f;

    int i_lo = g * 67;
    int i_hi = (i_lo + 67 < 529) ? i_lo + 67 : 529;
#pragma unroll 1
    for (int i = i_lo; i < i_hi; ++i) {
        int iu = __builtin_amdgcn_readfirstlane(i);   // provably wave-uniform
        float xv = xp[(size_t)iu * 16];
        float f[9];
        f[0] = siluf(xv);
        bspline8(xv, f + 1);
        const float* wp = w1t + (size_t)iu * 360;     // uniform -> s_load
#pragma unroll
        for (int q = 0; q < 9; ++q) {
            float fv = f[q];
            const float* wrow = wp + q * 40;
#pragma unroll
            for (int o = 0; o < 40; ++o)
                acc[o] = fmaf(fv, wrow[o], acc[o]);   // v_fmac v, s, v
        }
    }
#pragma unroll
    for (int o = 0; o < 40; ++o) part[g][o][r] = acc[o];
    __syncthreads();

    // layer2: wave oq = t>>6 handles o = oq + 8k; lane r2 = row.
    int oq = t >> 6;
    int r2 = t & 63;
    int cnt = (oq < 4) ? 8 : 7;
    float acc2[8];
#pragma unroll
    for (int k = 0; k < 8; ++k) acc2[k] = 0.f;

#pragma unroll 1
    for (int i = 0; i < 40; ++i) {
        float hv = part[0][i][r2] + part[1][i][r2] + part[2][i][r2] +
                   part[3][i][r2] + part[4][i][r2] + part[5][i][r2] +
                   part[6][i][r2] + part[7][i][r2];
        float f[9];
        f[0] = siluf(hv);
        bspline8(hv, f + 1);
        const float* wp = w2t + i * 540;              // uniform -> s_load
#pragma unroll
        for (int q = 0; q < 9; ++q) {
            float fv = f[q];
            const float* wrow = wp + q * 60 + oq;
#pragma unroll
            for (int k = 0; k < 8; ++k)
                if (k < cnt) acc2[k] = fmaf(fv, wrow[k * 8], acc2[k]);
        }
    }
    float* op = h2d + (size_t)(n0 + (r2 >> 4)) * 960 + (r2 & 15);
#pragma unroll
    for (int k = 0; k < 8; ++k)
        if (k < cnt) op[(size_t)(oq + k * 8) * 16] = acc2[k];
}

// ---------------------------------------------------------------------------
// k_lin1head: 256 blocks x 512 threads, block = 8 rows. Stage H in LDS,
// thread owns u = t (8 row-accs), h3 back into LDS, wave = one head row.
// ---------------------------------------------------------------------------
__global__ __launch_bounds__(512) void k_lin1head(
    const float* __restrict__ h2d, const float* __restrict__ wq,
    const float* __restrict__ lin1_b, const float* __restrict__ act_base,
    const float* __restrict__ act_coeff, const float* __restrict__ lin2_w,
    const float* __restrict__ lin2_b, float* __restrict__ out) {
    __shared__ float smem[8 * 960];   // 30.7 KB; reused as h3[8][512]
    int t = threadIdx.x;
    int n0 = blockIdx.x * 8;

#pragma unroll 1
    for (int e = t; e < 7680; e += 512)
        smem[e] = h2d[(size_t)n0 * 960 + e];
    __syncthreads();

    float acc[8];
#pragma unroll
    for (int nn = 0; nn < 8; ++nn) acc[nn] = 0.f;

    const float4* wq4 = (const float4*)wq;
#pragma unroll 1
    for (int dq = 0; dq < 240; ++dq) {
        float4 wv = wq4[(size_t)dq * 512 + t];
#pragma unroll
        for (int nn = 0; nn < 8; ++nn) {
            float4 rv = *(const float4*)&smem[nn * 960 + dq * 4];  // broadcast
            float a = acc[nn];
            a = fmaf(rv.x, wv.x, a);
            a = fmaf(rv.y, wv.y, a);
            a = fmaf(rv.z, wv.z, a);
            a = fmaf(rv.w, wv.w, a);
            acc[nn] = a;
        }
    }
    float bu = lin1_b[t];
    __syncthreads();
#pragma unroll
    for (int nn = 0; nn < 8; ++nn)
        smem[nn * 512 + t] = acc[nn] + bu;
    __syncthreads();

    int wv = t >> 6, lane = t & 63;
    int n = n0 + wv;
    const float* hr = smem + wv * 512;

    float xv[8];
#pragma unroll
    for (int k = 0; k < 8; ++k) xv[k] = hr[lane + 64 * k];
    float ss = 0.f;
#pragma unroll
    for (int k = 0; k < 8; ++k) ss = fmaf(xv[k], xv[k], ss);
#pragma unroll
    for (int d = 1; d < 64; d <<= 1) ss += __shfl_xor(ss, d, 64);
    float scale = 1.f / fmaxf(sqrtf(ss), 1e-12f);

    float act[8];
#pragma unroll
    for (int k = 0; k < 8; ++k) {
        int u = lane + 64 * k;
        float hn = xv[k] * scale;
        float s = siluf(hn);
        float fm[8];
        bspline8(hn, fm);
        float4 c0 = *(const float4*)(act_coeff + (size_t)u * 8);
        float4 c1 = *(const float4*)(act_coeff + (size_t)u * 8 + 4);
        float a = act_base[u] * s;
        a = fmaf(fm[0], c0.x, a);
        a = fmaf(fm[1], c0.y, a);
        a = fmaf(fm[2], c0.z, a);
        a = fmaf(fm[3], c0.w, a);
        a = fmaf(fm[4], c1.x, a);
        a = fmaf(fm[5], c1.y, a);
        a = fmaf(fm[6], c1.z, a);
        a = fmaf(fm[7], c1.w, a);
        act[k] = a;
    }

    float y = 0.f;
#pragma unroll
    for (int v = 0; v < 16; ++v) {
        float pv = 0.f;
#pragma unroll
        for (int k = 0; k < 8; ++k)
            pv = fmaf(act[k], lin2_w[v * 512 + lane + 64 * k], pv);
#pragma unroll
        for (int d = 1; d < 64; d <<= 1) pv += __shfl_xor(pv, d, 64);
        if (lane == v) y = pv + lin2_b[v];
    }
    float qq = y * y;                 // lanes >= 16 hold y = 0
#pragma unroll
    for (int d = 1; d < 16; d <<= 1) qq += __shfl_xor(qq, d, 64);
    float sc2 = 1.f / fmaxf(sqrtf(qq), 1e-12f);
    if (lane < 16)
        out[(size_t)n * 16 + lane] = y * sc2;
}

// ---------------------------------------------------------------------------
extern "C" void kernel_launch(void* const* d_in, const int* in_sizes, int n_in,
                              void* d_out, int out_size, void* d_ws,
                              size_t ws_size, hipStream_t stream) {
    auto find = [&](int sz, int occur) -> const float* {
        int seen = 0;
        for (int i = 0; i < n_in; ++i) {
            if (in_sizes[i] == sz) {
                if (seen == occur) return (const float*)d_in[i];
                ++seen;
            }
        }
        return nullptr;
    };
    const float* x         = find(17334272, 0);
    const float* base_w1   = find(21160, 0);
    const float* spline_w1 = find(169280, 0);
    const float* base_w2   = find(2400, 0);
    const float* spline_w2 = find(19200, 0);
    const float* lin1_w    = find(491520, 0);
    const float* lin1_b    = find(512, 0);
    const float* act_base  = find(512, 1);
    const float* act_coeff = find(4096, 0);
    const float* lin2_w    = find(8192, 0);
    const float* lin2_b    = find(16, 0);
    if (!x || !base_w1 || !spline_w1 || !base_w2 || !spline_w2 || !lin1_w ||
        !lin1_b || !act_base || !act_coeff || !lin2_w || !lin2_b) {
        x         = (const float*)d_in[0];
        base_w1   = (const float*)d_in[3];
        spline_w1 = (const float*)d_in[4];
        base_w2   = (const float*)d_in[6];
        spline_w2 = (const float*)d_in[7];
        lin1_w    = (const float*)d_in[8];
        lin1_b    = (const float*)d_in[9];
        act_base  = (const float*)d_in[11];
        act_coeff = (const float*)d_in[12];
        lin2_w    = (const float*)d_in[13];
        lin2_b    = (const float*)d_in[14];
    }

    float* ws  = (float*)d_ws;
    float* w1t = ws;                 // 529*360    = 190440 floats
    float* w2t = w1t + 190440;       // 40*540     = 21600
    float* wq  = w2t + 21600;        // 240*512*4  = 491520
    float* h2d = wq + 491520;        // 2048*960   = 1966080
    // total 2,669,640 floats = 10.2 MB

    k_prep<<<1024, 256, 0, stream>>>(base_w1, spline_w1, base_w2, spline_w2,
                                     lin1_w, w1t, w2t, wq);
    k_l12<<<512, 512, 0, stream>>>(x, w1t, w2t, h2d);
    k_lin1head<<<256, 512, 0, stream>>>(h2d, wq, lin1_b, act_base, act_coeff,
                                        lin2_w, lin2_b, (float*)d_out);
}

// Round 6
// 479.252 us; speedup vs baseline: 4.5865x; 1.0729x over previous
//
#include <hip/hip_runtime.h>

// ---------------------------------------------------------------------------
// KAN net. gr = n*16 + w row ordering; xa[gr,i] = x[n*8464 + i*16 + w].
// k_l1:  layer1 (32768,529)->(32768,40) via bf16x2 (hi/lo) MFMA 16x16x32,
//        A-fragments computed in registers (silu+bspline per lane), B
//        pre-packed in fragment order by k_prep. 2-way K-split -> h1p[2].
// k_l2:  sum partials, layer2 (40->60) f32 VALU -> h2d[n][o*16+w]
// k_lin1head: lin1(960->512)+l2norm+spline act+lin2+l2norm -> f32 out (r5).
// ---------------------------------------------------------------------------

typedef short bf16x8 __attribute__((ext_vector_type(8)));
typedef float f32x4 __attribute__((ext_vector_type(4)));

__device__ __forceinline__ float siluf(float x) { return x / (1.f + __expf(-x)); }

__device__ __forceinline__ unsigned short f2bf(float v) {
    union { float f; unsigned u; } a; a.f = v;
    return (unsigned short)((a.u + 0x7fffu + ((a.u >> 16) & 1u)) >> 16);  // RNE
}
__device__ __forceinline__ float bf2f(unsigned short h) {
    union { unsigned u; float f; } a; a.u = ((unsigned)h) << 16;
    return a.f;
}

// Dense 8-wide cubic B-spline, uniform grid t_j=(j-3)*0.4-1 (validated vs
// literal Cox-de Boor in the r2 bisection build).
__device__ __forceinline__ void bspline8(float x, float fm[8]) {
    float tpos = (x + 2.2f) * 2.5f;
    float fc = floorf(tpos);
    int c = (int)fc;
    float u = tpos - fc;
    bool valid = (c >= 0) && (c <= 10);
    float om = 1.f - u;
    float u2 = u * u, u3 = u2 * u;
    float W0 = om * om * om * (1.f / 6.f);
    float W1 = (3.f * u3 - 6.f * u2 + 4.f) * (1.f / 6.f);
    float W2 = (-3.f * u3 + 3.f * u2 + 3.f * u + 1.f) * (1.f / 6.f);
    float W3 = u3 * (1.f / 6.f);
#pragma unroll
    for (int m = 0; m < 8; ++m) {
        int d = c - m;
        float v = (d == 3) ? W0 : 0.f;
        v = (d == 2) ? W1 : v;
        v = (d == 1) ? W2 : v;
        v = (d == 0) ? W3 : v;
        fm[m] = valid ? v : 0.f;
    }
}

// ---------------------------------------------------------------------------
// k_prep:
//  bhi/blo[((G*3+nt)*64+l)*8+j] = bf16 split of B[k=G*32+(l>>4)*8+j][n=nt*16+(l&15)]
//     with k-space: i = k>>4, q = k&15; q0=base_w1, q1..8=spline_w1, else 0.
//  w2t[i][q][60]; wq[dq][u][4] = lin1_w[u][dq*4+r]
// ---------------------------------------------------------------------------
__global__ __launch_bounds__(256) void k_prep(
    const float* __restrict__ base_w1, const float* __restrict__ spline_w1,
    const float* __restrict__ base_w2, const float* __restrict__ spline_w2,
    const float* __restrict__ lin1_w,
    unsigned short* __restrict__ bhi, unsigned short* __restrict__ blo,
    float* __restrict__ w2t, float* __restrict__ wq) {
    int gid = blockIdx.x * 256 + threadIdx.x;
    int stride = gridDim.x * 256;
    for (int idx = gid; idx < 272 * 3 * 512; idx += stride) {
        int j = idx & 7;
        int l = (idx >> 3) & 63;
        int ntG = idx >> 9;
        int nt = ntG % 3;
        int G = ntG / 3;
        int k = G * 32 + ((l >> 4) << 3) + j;
        int i = k >> 4;
        int q = k & 15;
        int n = nt * 16 + (l & 15);
        float val = 0.f;
        if (i < 529 && n < 40 && q <= 8)
            val = (q == 0) ? base_w1[n * 529 + i]
                           : spline_w1[(n * 529 + i) * 8 + (q - 1)];
        unsigned short h = f2bf(val);
        bhi[idx] = h;
        blo[idx] = f2bf(val - bf2f(h));
    }
    for (int idx = gid; idx < 40 * 540; idx += stride) {
        int i = idx / 540;
        int rem = idx - i * 540;
        int q = rem / 60;
        int o = rem - q * 60;
        w2t[idx] = (q == 0) ? base_w2[o * 40 + i]
                            : spline_w2[(o * 40 + i) * 8 + (q - 1)];
    }
    for (int idx = gid; idx < 240 * 512 * 4; idx += stride) {
        int dq = idx >> 11;
        int rem = idx & 2047;
        int u = rem >> 2;
        int r = rem & 3;
        wq[idx] = lin1_w[u * 960 + dq * 4 + r];
    }
}

// ---------------------------------------------------------------------------
// k_l1: 1024 blocks x 256 thr. block -> (m = bx>>1: 4 n's, half = bx&1: K half).
// Wave wv handles n = m*4+wv, i.e. m-tile rows r = w = 0..15 (gr = n*16+w).
// Per kstep ks: k = ks*32 + (l>>4)*8 + j; i = ks*2 + (l>>5); q = (l>>4&1)*8+j.
// Lane computes features f32, splits to bf16 hi/lo, 9 MFMAs (3 nt x 3 split).
// ---------------------------------------------------------------------------
__global__ __launch_bounds__(256) void k_l1(
    const float* __restrict__ x, const unsigned short* __restrict__ bhi,
    const unsigned short* __restrict__ blo, float* __restrict__ h1p) {
    int t = threadIdx.x;
    int l = t & 63;
    int wv = t >> 6;
    int m = blockIdx.x >> 1;
    int half = blockIdx.x & 1;
    int n = m * 4 + wv;
    int col = l & 15;          // A-row (= w) during compute; N-col at store
    int grp = l >> 4;
    int isub = grp >> 1;
    bool hiQ = (grp & 1) != 0;
    const float* xrow = x + (size_t)n * 8464 + col;

    f32x4 acc0 = {0.f, 0.f, 0.f, 0.f};
    f32x4 acc1 = {0.f, 0.f, 0.f, 0.f};
    f32x4 acc2 = {0.f, 0.f, 0.f, 0.f};

    int ks0 = half * 136;
    int i_cur = ks0 * 2 + isub;
    float xv_cur = (i_cur < 529) ? xrow[(size_t)i_cur * 16] : 0.f;

#pragma unroll 1
    for (int ks = ks0; ks < ks0 + 136; ++ks) {
        int i = ks * 2 + isub;
        float xv = xv_cur;
        {   // prefetch next
            int i_n = i + 2;
            xv_cur = (ks + 1 < ks0 + 136 && i_n < 529) ? xrow[(size_t)i_n * 16] : 0.f;
        }
        float f[9];
        f[0] = siluf(xv);
        bspline8(xv, f + 1);
        bool live = (i < 529);

        bf16x8 ahi, alo;
#pragma unroll
        for (int j = 0; j < 8; ++j) {
            float v = hiQ ? ((j == 0) ? f[8] : 0.f) : f[j];
            v = live ? v : 0.f;
            unsigned short h = f2bf(v);
            ahi[j] = (short)h;
            alo[j] = (short)f2bf(v - bf2f(h));
        }

        const bf16x8* bh = (const bf16x8*)(bhi + ((size_t)ks * 3) * 512 + (size_t)l * 8);
        const bf16x8* bl = (const bf16x8*)(blo + ((size_t)ks * 3) * 512 + (size_t)l * 8);
        bf16x8 bh0 = bh[0], bh1 = bh[64], bh2 = bh[128];
        bf16x8 bl0 = bl[0], bl1 = bl[64], bl2 = bl[128];

        acc0 = __builtin_amdgcn_mfma_f32_16x16x32_bf16(ahi, bh0, acc0, 0, 0, 0);
        acc1 = __builtin_amdgcn_mfma_f32_16x16x32_bf16(ahi, bh1, acc1, 0, 0, 0);
        acc2 = __builtin_amdgcn_mfma_f32_16x16x32_bf16(ahi, bh2, acc2, 0, 0, 0);
        acc0 = __builtin_amdgcn_mfma_f32_16x16x32_bf16(ahi, bl0, acc0, 0, 0, 0);
        acc1 = __builtin_amdgcn_mfma_f32_16x16x32_bf16(ahi, bl1, acc1, 0, 0, 0);
        acc2 = __builtin_amdgcn_mfma_f32_16x16x32_bf16(ahi, bl2, acc2, 0, 0, 0);
        acc0 = __builtin_amdgcn_mfma_f32_16x16x32_bf16(alo, bh0, acc0, 0, 0, 0);
        acc1 = __builtin_amdgcn_mfma_f32_16x16x32_bf16(alo, bh1, acc1, 0, 0, 0);
        acc2 = __builtin_amdgcn_mfma_f32_16x16x32_bf16(alo, bh2, acc2, 0, 0, 0);
    }

    // store: D[r][c]: c = l&15 (o-col), r = 4*(l>>4)+reg (w-row)
    float* hp = h1p + (size_t)half * 1310720;
#pragma unroll
    for (int reg = 0; reg < 4; ++reg) {
        int r = grp * 4 + reg;
        size_t gr = (size_t)n * 16 + r;
        if (col < 8) {  // nt=2 only cols 0..7 are real (o = 32..39)
            hp[gr * 40 + 32 + col] = acc2[reg];
        }
        hp[gr * 40 + col] = acc0[reg];
        hp[gr * 40 + 16 + col] = acc1[reg];
    }
}

// ---------------------------------------------------------------------------
// k_l2: 512 blocks (128 rowchunks x 4 o-quarters) x 256 thr. Stage+sum the
// two K-half partials in LDS (stride 41), thread = one row, 15 outputs.
// ---------------------------------------------------------------------------
__global__ __launch_bounds__(256) void k_l2(
    const float* __restrict__ h1p, const float* __restrict__ w2t,
    float* __restrict__ h2d) {
    __shared__ float lds[256 * 41];
    int t = threadIdx.x;
    int rc = blockIdx.x >> 2;
    int oq = blockIdx.x & 3;
    size_t base = (size_t)rc * 10240;

#pragma unroll 1
    for (int e = t; e < 10240; e += 256) {
        int r = e / 40;
        int i = e - r * 40;
        lds[r * 41 + i] = h1p[base + e] + h1p[1310720 + base + e];
    }
    __syncthreads();

    float acc[15];
#pragma unroll
    for (int oo = 0; oo < 15; ++oo) acc[oo] = 0.f;

#pragma unroll 1
    for (int i = 0; i < 40; ++i) {
        float hv = lds[t * 41 + i];
        float f[9];
        f[0] = siluf(hv);
        bspline8(hv, f + 1);
        const float* wp = w2t + i * 540 + oq * 15;   // uniform -> s_load
#pragma unroll
        for (int q = 0; q < 9; ++q) {
            float fv = f[q];
#pragma unroll
            for (int oo = 0; oo < 15; ++oo)
                acc[oo] = fmaf(fv, wp[q * 60 + oo], acc[oo]);
        }
    }
    int gr = rc * 256 + t;
    int n = gr >> 4, w = gr & 15;
    float* op = h2d + (size_t)n * 960 + w;
#pragma unroll
    for (int oo = 0; oo < 15; ++oo)
        op[(size_t)(oq * 15 + oo) * 16] = acc[oo];
}

// ---------------------------------------------------------------------------
// k_lin1head (r5, passing): 256 blocks x 512 thr, block = 8 rows.
// ---------------------------------------------------------------------------
__global__ __launch_bounds__(512) void k_lin1head(
    const float* __restrict__ h2d, const float* __restrict__ wq,
    const float* __restrict__ lin1_b, const float* __restrict__ act_base,
    const float* __restrict__ act_coeff, const float* __restrict__ lin2_w,
    const float* __restrict__ lin2_b, float* __restrict__ out) {
    __shared__ float smem[8 * 960];
    int t = threadIdx.x;
    int n0 = blockIdx.x * 8;

#pragma unroll 1
    for (int e = t; e < 7680; e += 512)
        smem[e] = h2d[(size_t)n0 * 960 + e];
    __syncthreads();

    float acc[8];
#pragma unroll
    for (int nn = 0; nn < 8; ++nn) acc[nn] = 0.f;

    const float4* wq4 = (const float4*)wq;
#pragma unroll 1
    for (int dq = 0; dq < 240; ++dq) {
        float4 wv = wq4[(size_t)dq * 512 + t];
#pragma unroll
        for (int nn = 0; nn < 8; ++nn) {
            float4 rv = *(const float4*)&smem[nn * 960 + dq * 4];
            float a = acc[nn];
            a = fmaf(rv.x, wv.x, a);
            a = fmaf(rv.y, wv.y, a);
            a = fmaf(rv.z, wv.z, a);
            a = fmaf(rv.w, wv.w, a);
            acc[nn] = a;
        }
    }
    float bu = lin1_b[t];
    __syncthreads();
#pragma unroll
    for (int nn = 0; nn < 8; ++nn)
        smem[nn * 512 + t] = acc[nn] + bu;
    __syncthreads();

    int wv = t >> 6, lane = t & 63;
    int n = n0 + wv;
    const float* hr = smem + wv * 512;

    float xv[8];
#pragma unroll
    for (int k = 0; k < 8; ++k) xv[k] = hr[lane + 64 * k];
    float ss = 0.f;
#pragma unroll
    for (int k = 0; k < 8; ++k) ss = fmaf(xv[k], xv[k], ss);
#pragma unroll
    for (int d = 1; d < 64; d <<= 1) ss += __shfl_xor(ss, d, 64);
    float scale = 1.f / fmaxf(sqrtf(ss), 1e-12f);

    float act[8];
#pragma unroll
    for (int k = 0; k < 8; ++k) {
        int u = lane + 64 * k;
        float hn = xv[k] * scale;
        float s = siluf(hn);
        float fm[8];
        bspline8(hn, fm);
        float4 c0 = *(const float4*)(act_coeff + (size_t)u * 8);
        float4 c1 = *(const float4*)(act_coeff + (size_t)u * 8 + 4);
        float a = act_base[u] * s;
        a = fmaf(fm[0], c0.x, a);
        a = fmaf(fm[1], c0.y, a);
        a = fmaf(fm[2], c0.z, a);
        a = fmaf(fm[3], c0.w, a);
        a = fmaf(fm[4], c1.x, a);
        a = fmaf(fm[5], c1.y, a);
        a = fmaf(fm[6], c1.z, a);
        a = fmaf(fm[7], c1.w, a);
        act[k] = a;
    }

    float y = 0.f;
#pragma unroll
    for (int v = 0; v < 16; ++v) {
        float pv = 0.f;
#pragma unroll
        for (int k = 0; k < 8; ++k)
            pv = fmaf(act[k], lin2_w[v * 512 + lane + 64 * k], pv);
#pragma unroll
        for (int d = 1; d < 64; d <<= 1) pv += __shfl_xor(pv, d, 64);
        if (lane == v) y = pv + lin2_b[v];
    }
    float qq = y * y;
#pragma unroll
    for (int d = 1; d < 16; d <<= 1) qq += __shfl_xor(qq, d, 64);
    float sc2 = 1.f / fmaxf(sqrtf(qq), 1e-12f);
    if (lane < 16)
        out[(size_t)n * 16 + lane] = y * sc2;
}

// ---------------------------------------------------------------------------
extern "C" void kernel_launch(void* const* d_in, const int* in_sizes, int n_in,
                              void* d_out, int out_size, void* d_ws,
                              size_t ws_size, hipStream_t stream) {
    auto find = [&](int sz, int occur) -> const float* {
        int seen = 0;
        for (int i = 0; i < n_in; ++i) {
            if (in_sizes[i] == sz) {
                if (seen == occur) return (const float*)d_in[i];
                ++seen;
            }
        }
        return nullptr;
    };
    const float* x         = find(17334272, 0);
    const float* base_w1   = find(21160, 0);
    const float* spline_w1 = find(169280, 0);
    const float* base_w2   = find(2400, 0);
    const float* spline_w2 = find(19200, 0);
    const float* lin1_w    = find(491520, 0);
    const float* lin1_b    = find(512, 0);
    const float* act_base  = find(512, 1);
    const float* act_coeff = find(4096, 0);
    const float* lin2_w    = find(8192, 0);
    const float* lin2_b    = find(16, 0);
    if (!x || !base_w1 || !spline_w1 || !base_w2 || !spline_w2 || !lin1_w ||
        !lin1_b || !act_base || !act_coeff || !lin2_w || !lin2_b) {
        x         = (const float*)d_in[0];
        base_w1   = (const float*)d_in[3];
        spline_w1 = (const float*)d_in[4];
        base_w2   = (const float*)d_in[6];
        spline_w2 = (const float*)d_in[7];
        lin1_w    = (const float*)d_in[8];
        lin1_b    = (const float*)d_in[9];
        act_base  = (const float*)d_in[11];
        act_coeff = (const float*)d_in[12];
        lin2_w    = (const float*)d_in[13];
        lin2_b    = (const float*)d_in[14];
    }

    char* ws = (char*)d_ws;
    float* w2t = (float*)ws;                          // 21600 f    = 86400 B
    float* wq  = (float*)(ws + 86400);                // 491520 f   = 1966080 B
    float* h2d = (float*)(ws + 86400 + 1966080);      // 1966080 f  = 7864320 B
    float* h1p = (float*)(ws + 86400 + 1966080 + 7864320);          // 2x1310720 f
    unsigned short* bhi = (unsigned short*)(ws + 86400 + 1966080 + 7864320 + 10485760);
    unsigned short* blo = bhi + 417792;               // 2 x 835584 B
    // total 22,073,728 B (r0 proved >= 30.7 MB usable)

    k_prep<<<1024, 256, 0, stream>>>(base_w1, spline_w1, base_w2, spline_w2,
                                     lin1_w, bhi, blo, w2t, wq);
    k_l1<<<1024, 256, 0, stream>>>(x, bhi, blo, h1p);
    k_l2<<<512, 256, 0, stream>>>(h1p, w2t, h2d);
    k_lin1head<<<256, 512, 0, stream>>>(h2d, wq, lin1_b, act_base, act_coeff,
                                        lin2_w, lin2_b, (float*)d_out);
}